// Round 5
// baseline (81.485 us; speedup 1.0000x reference)
//
#include <hip/hip_runtime.h>
#include <hip/hip_bf16.h>

// 32 graphs x 128 nodes, F=64, HID=128, OUT=64
#define F_IN 64
#define HID 128
#define OUTF 64
#define NN 128
#define NB 32
#define TOTAL 4096

typedef short bf16x8 __attribute__((ext_vector_type(8)));
typedef float f32x4 __attribute__((ext_vector_type(4)));
typedef float f32x2 __attribute__((ext_vector_type(2)));
typedef unsigned int u32x2 __attribute__((ext_vector_type(2)));

static __device__ __forceinline__ short f2bf(float v) {
  __hip_bfloat16 h = __float2bfloat16(v);
  return __builtin_bit_cast(short, h);
}

// silu on a pair: ONE transcendental per element (exp). Reciprocal of
// (1+e^-v) via bit-trick seed + 2 Newton steps (rel err ~6e-6 << bf16 ulp).
static __device__ __forceinline__ f32x2 silu2(f32x2 v) {
  f32x2 e;
  e.x = fminf(__expf(-v.x), 1e13f);  // guard inf so Newton can't NaN
  e.y = fminf(__expf(-v.y), 1e13f);
  f32x2 x = e + 1.f;
  u32x2 yi = (u32x2)(0x7EF311C3u) - __builtin_bit_cast(u32x2, x);
  f32x2 y = __builtin_bit_cast(f32x2, yi);
  y = y * (2.f - x * y);
  y = y * (2.f - x * y);
  return v * y;
}

// ---------------------------------------------------------------------------
// uv_prep: 256 blocks x 256 thr. Block handles 16 nodes.
//   uv[n][c] = h[n]@Wcat[:,c]  (c<128: u = h@W1[1:65]; c>=128: v = h@W1[65:129]+b1)
// Blocks 0-63 also emit swizzled bf16 W2^T (w2swz).
// ---------------------------------------------------------------------------
__global__ __launch_bounds__(256) void uv_prep(
    const float* __restrict__ feat,
    const float* __restrict__ W1,
    const float* __restrict__ W2,
    const float* __restrict__ b1,
    float* __restrict__ uv,
    __hip_bfloat16* __restrict__ w2swz) {
  __shared__ __align__(16) char wcat[256 * 128];
  const int tid = threadIdx.x;
  {
    const int c = tid;
    const int cc = c & 127;
    const int rbase = (c < HID) ? 1 : 65;
#pragma unroll
    for (int p = 0; p < 8; ++p) {
      bf16x8 pk;
#pragma unroll
      for (int m = 0; m < 8; ++m)
        pk[m] = f2bf(W1[(rbase + p * 8 + m) * HID + cc]);
      *reinterpret_cast<bf16x8*>(wcat + c * 128 + ((p ^ (c & 7)) << 4)) = pk;
    }
  }
  if (blockIdx.x < 64) {
    const int e = blockIdx.x * 256 + tid;
    const int kk = e >> 7, cc2 = e & 127;
    const int byo = cc2 * 256 + (((kk >> 3) ^ (cc2 & 7)) << 4) + (kk & 7) * 2;
    *reinterpret_cast<__hip_bfloat16*>(reinterpret_cast<char*>(w2swz) + byo) =
        __float2bfloat16(W2[kk * HID + cc2]);
  }
  __syncthreads();

  const int wave = tid >> 6, lane = tid & 63;
  const int lr = lane & 15, kg = lane >> 4;
  const int r0 = blockIdx.x * 16;

  f32x4 acc[4];
#pragma unroll
  for (int ct = 0; ct < 4; ++ct) acc[ct] = {0.f, 0.f, 0.f, 0.f};

#pragma unroll
  for (int ks = 0; ks < 2; ++ks) {
    const float* fp = feat + (size_t)(r0 + lr) * F_IN + ks * 32 + kg * 8;
    const f32x4 fa = *reinterpret_cast<const f32x4*>(fp);
    const f32x4 fb = *reinterpret_cast<const f32x4*>(fp + 4);
    bf16x8 a;
#pragma unroll
    for (int m = 0; m < 4; ++m) {
      a[m] = f2bf(fa[m]);
      a[4 + m] = f2bf(fb[m]);
    }
    const int slot = ks * 4 + kg;
#pragma unroll
    for (int ct = 0; ct < 4; ++ct) {
      const int c = wave * 64 + ct * 16 + lr;
      const bf16x8 w = *reinterpret_cast<const bf16x8*>(
          wcat + c * 128 + ((slot ^ (c & 7)) << 4));
      acc[ct] = __builtin_amdgcn_mfma_f32_16x16x32_bf16(a, w, acc[ct], 0, 0, 0);
    }
  }
#pragma unroll
  for (int ct = 0; ct < 4; ++ct) {
    const int c = wave * 64 + ct * 16 + lr;
    const float badd = (c >= HID) ? b1[c - HID] : 0.f;
#pragma unroll
    for (int reg = 0; reg < 4; ++reg) {
      const int r = r0 + kg * 4 + reg;
      uv[(size_t)r * 256 + c] = acc[ct][reg] + badd;
    }
  }
}

// ---------------------------------------------------------------------------
// main: 2048 blocks = (graph b, pair of i) x 512 thr (8 waves).
// Wave tile: 32 rows x 128 cols -> acc[2][8] = 64 f32/lane (vs 128 in r4),
// target ~3 waves/SIMD. One-trans silu + pk-f32 math. B-frags in regs,
// reused by 2 A-tiles.
// ---------------------------------------------------------------------------
__global__ __launch_bounds__(512, 2) void sake_main(
    const float* __restrict__ coord,
    const float* __restrict__ W1,   // row 0 = d2 weights
    const float* __restrict__ b2,
    const float* __restrict__ uv,
    const __hip_bfloat16* __restrict__ w2swz,
    float* __restrict__ part) {
  __shared__ __align__(16) char w2lds[HID * 256];  // 32 KB pre-swizzled
  __shared__ float ssum[8][HID];

  const int tid = threadIdx.x;
  // XCD swizzle: 2048 = 8 XCD x 256; 4 graphs per XCD
  const int bid = (blockIdx.x & 7) * 256 + (blockIdx.x >> 3);
  const int b = bid >> 6;
  const int i0 = (bid & 63) * 2;

  // stage pre-swizzled W2 -> LDS (linear copy)
#pragma unroll
  for (int p = 0; p < 4; ++p) {
    const int o = (tid + p * 512) * 16;
    *reinterpret_cast<int4*>(w2lds + o) =
        *reinterpret_cast<const int4*>(reinterpret_cast<const char*>(w2swz) + o);
  }

  const int wave = tid >> 6, lane = tid & 63;
  const int lr = lane & 15, kg = lane >> 4;
  const int i = i0 + (wave >> 2);      // waves 0-3 -> i0, 4-7 -> i0+1
  const int j0 = (wave & 3) * 32;      // j-quarter

  // d2 for this thread's 2 rows (exact f32)
  const float* xi = coord + (size_t)(b * NN + i) * 3;
  const float xix = xi[0], xiy = xi[1], xiz = xi[2];
  float d2t[2];
#pragma unroll
  for (int t = 0; t < 2; ++t) {
    const float* xj = coord + (size_t)(b * NN + j0 + t * 16 + lr) * 3;
    const float dx = xj[0] - xix, dy = xj[1] - xiy, dz = xj[2] - xiz;
    d2t[t] = dx * dx + dy * dy + dz * dz;
  }

  f32x4 acc[2][8];
#pragma unroll
  for (int ct = 0; ct < 8; ++ct) {
    const float bb = b2[ct * 16 + lr];
#pragma unroll
    for (int t = 0; t < 2; ++t) acc[t][ct] = {bb, bb, bb, bb};
  }

  const float* vrow = uv + ((size_t)b * NN + i) * 256 + HID;
  const float* urow0 = uv + ((size_t)b * NN + j0 + lr) * 256;

  __syncthreads();  // w2lds ready

#pragma unroll
  for (int ks = 0; ks < 4; ++ks) {
    const int c0 = ks * 32 + kg * 8;
    // B-fragments for this ks (8 frags, reused by both A-tiles)
    bf16x8 wf[8];
    const int rbase = lr * 256 + ((((ks << 2) | kg) ^ (lr & 7)) << 4);
#pragma unroll
    for (int ct = 0; ct < 8; ++ct)
      wf[ct] = *reinterpret_cast<const bf16x8*>(w2lds + rbase + ct * 4096);

    // per-ks v and w0 as pairs
    const f32x4 va = *reinterpret_cast<const f32x4*>(vrow + c0);
    const f32x4 vb = *reinterpret_cast<const f32x4*>(vrow + c0 + 4);
    const f32x4 wa = *reinterpret_cast<const f32x4*>(W1 + c0);
    const f32x4 wb = *reinterpret_cast<const f32x4*>(W1 + c0 + 4);
    f32x2 vp2[4] = {__builtin_shufflevector(va, va, 0, 1),
                    __builtin_shufflevector(va, va, 2, 3),
                    __builtin_shufflevector(vb, vb, 0, 1),
                    __builtin_shufflevector(vb, vb, 2, 3)};
    f32x2 wp2[4] = {__builtin_shufflevector(wa, wa, 0, 1),
                    __builtin_shufflevector(wa, wa, 2, 3),
                    __builtin_shufflevector(wb, wb, 0, 1),
                    __builtin_shufflevector(wb, wb, 2, 3)};

#pragma unroll
    for (int t = 0; t < 2; ++t) {
      const float* up = urow0 + t * 4096 + c0;  // row j0 + t*16 + lr
      const f32x4 ua = *reinterpret_cast<const f32x4*>(up);
      const f32x4 ub = *reinterpret_cast<const f32x4*>(up + 4);
      f32x2 up2[4] = {__builtin_shufflevector(ua, ua, 0, 1),
                      __builtin_shufflevector(ua, ua, 2, 3),
                      __builtin_shufflevector(ub, ub, 0, 1),
                      __builtin_shufflevector(ub, ub, 2, 3)};
      const f32x2 d2v = {d2t[t], d2t[t]};
      bf16x8 a;
#pragma unroll
      for (int p = 0; p < 4; ++p) {
        f32x2 z = up2[p] + vp2[p];
        z = d2v * wp2[p] + z;          // pk fma
        const f32x2 s = silu2(z);
        a[2 * p] = f2bf(s.x);
        a[2 * p + 1] = f2bf(s.y);
      }
#pragma unroll
      for (int ct = 0; ct < 8; ++ct)
        acc[t][ct] = __builtin_amdgcn_mfma_f32_16x16x32_bf16(a, wf[ct],
                                                             acc[t][ct], 0, 0, 0);
    }
  }

  // silu(z2) + column sums over this wave's 32 rows
  float csum[8];
#pragma unroll
  for (int ct = 0; ct < 8; ++ct) {
    f32x2 sp = {0.f, 0.f};
#pragma unroll
    for (int t = 0; t < 2; ++t) {
      const f32x4 av = acc[t][ct];
      sp += silu2(__builtin_shufflevector(av, av, 0, 1));
      sp += silu2(__builtin_shufflevector(av, av, 2, 3));
    }
    float s = sp.x + sp.y;
    s += __shfl_xor(s, 16);
    s += __shfl_xor(s, 32);
    csum[ct] = s;
  }
  if (lane < 16) {
#pragma unroll
    for (int ct = 0; ct < 8; ++ct) ssum[wave][ct * 16 + lane] = csum[ct];
  }
  __syncthreads();
  if (tid < HID) {
    float s = 0.f;
#pragma unroll
    for (int w = 0; w < 8; ++w) s += ssum[w][tid];
    part[(size_t)bid * HID + tid] = s;  // partial: 2 i-rows x 128 j summed
  }
}

// ---------------------------------------------------------------------------
// final: out[b] = (sum_{g<64} part[b*64+g]) @ W3 + 16384*b3   (all f32, exact)
// ---------------------------------------------------------------------------
__global__ void final_kernel(const float* __restrict__ part,
                             const float* __restrict__ W3,
                             const float* __restrict__ b3,
                             float* __restrict__ out) {
  __shared__ float s2[2][HID];
  __shared__ float s[HID];
  int b = blockIdx.x, t = threadIdx.x;
  int c = t & 127, half = t >> 7;
  float a = 0.f;
  for (int g = half * 32; g < half * 32 + 32; ++g)
    a += part[(size_t)(b * 64 + g) * HID + c];
  s2[half][c] = a;
  __syncthreads();
  if (t < HID) s[t] = s2[0][t] + s2[1][t];
  __syncthreads();
  if (t < OUTF) {
    float o = 16384.f * b3[t];
    for (int c2 = 0; c2 < HID; ++c2) o += s[c2] * W3[c2 * OUTF + t];
    out[b * OUTF + t] = o;
  }
}

// ---------------------------------------------------------------------------
extern "C" void kernel_launch(void* const* d_in, const int* in_sizes, int n_in,
                              void* d_out, int out_size, void* d_ws, size_t ws_size,
                              hipStream_t stream) {
  const float* feat = (const float*)d_in[0];
  const float* coord = (const float*)d_in[1];
  const float* W1 = (const float*)d_in[2];
  const float* b1 = (const float*)d_in[3];
  const float* W2 = (const float*)d_in[4];
  const float* b2 = (const float*)d_in[5];
  const float* W3 = (const float*)d_in[6];
  const float* b3 = (const float*)d_in[7];
  float* out = (float*)d_out;

  char* ws = (char*)d_ws;
  __hip_bfloat16* w2swz = (__hip_bfloat16*)ws;            // 32 KB
  float* uv = (float*)(ws + 64 * 1024);                   // 4 MB
  float* part = (float*)(ws + 64 * 1024 + 4096 * 1024);   // 1 MB (2048 x 128)

  uv_prep<<<256, 256, 0, stream>>>(feat, W1, W2, b1, uv, w2swz);
  sake_main<<<2048, 512, 0, stream>>>(coord, W1, b2, uv, w2swz, part);
  final_kernel<<<NB, 256, 0, stream>>>(part, W3, b3, out);
}